// Round 10
// baseline (720.144 us; speedup 1.0000x reference)
//
#include <hip/hip_runtime.h>
#include <hip/hip_bf16.h>
#include <math.h>

// ---------------------------------------------------------------------------
// Quantized CNN forward (bitwise-exact vs fp32 reference):
//   block_k: maxpool2( quant_act( conv3x3(x, quant_weight(wk)), ak ) )
//   then global max over HxW, then 1x1 conv (10x128).
// Sparse formulation (R7+, absmax 0.0): ternary weights ~96% zero; zero-weight
// FMAs are skippable bitwise-safely; nonzeros applied (ci asc, k asc) per co.
//
// R10: R9 was LDS-instr-throughput bound with ~2.5x slot-padding inflation
// (per-chunk max over 16 co >> mean; total-nnz sorting can't fix it). New
// scheme: DENSE PER-CI REGISTER PATCH + EXACT LISTS. Per (group-of-16-co, ci)
// each thread loads its 4x4 patch once (8 aligned ds_read_b64 — covers all
// nine k stencils), then applies the exact entry list for that (group, ci)
// via a wave-uniform 144-case jump table on (co_local*9+k); coef is a runtime
// SGPR (+-s). No padding; LDS reads cut ~3x and widened to b64. Entry order
// (ci asc; co; k asc) keeps each co's accumulation in reference order.
// ---------------------------------------------------------------------------

__global__ __launch_bounds__(64)
void prep_zero(unsigned* __restrict__ maxb) {
    if (threadIdx.x < 4) maxb[threadIdx.x] = 0u;
}

__global__ __launch_bounds__(256)
void prep_absmax(const float* __restrict__ w1, const float* __restrict__ w2,
                 const float* __restrict__ w3, const float* __restrict__ wc,
                 unsigned* __restrict__ maxb) {
    const float* srcs[4] = {w1, w2, w3, wc};
    const int    ns[4]   = {32*3*9, 64*32*9, 128*64*9, 10*128};
    const int t = blockIdx.y;
    const float* s = srcs[t];
    const int    N = ns[t];
    float m = 0.f;
    for (int i = blockIdx.x * 256 + threadIdx.x; i < N; i += 16 * 256)
        m = fmaxf(m, fabsf(s[i]));
    #pragma unroll
    for (int o = 32; o > 0; o >>= 1) m = fmaxf(m, __shfl_down(m, o));
    __shared__ float red[4];
    const int lane = threadIdx.x & 63, wid = threadIdx.x >> 6;
    if (lane == 0) red[wid] = m;
    __syncthreads();
    if (threadIdx.x == 0) {
        float mm = fmaxf(fmaxf(red[0], red[1]), fmaxf(red[2], red[3]));
        atomicMax(maxb + t, __float_as_uint(mm));  // |w|>=0: uint order == float order
    }
}

__global__ __launch_bounds__(256)
void prep_quant(const float* __restrict__ w1, const float* __restrict__ w2,
                const float* __restrict__ w3, const float* __restrict__ wc,
                const unsigned* __restrict__ maxb,
                float* __restrict__ q1, float* __restrict__ q2,
                float* __restrict__ q3, float* __restrict__ qc) {
    const float* srcs[4] = {w1, w2, w3, wc};
    float*       dsts[4] = {q1, q2, q3, qc};
    const int    ns[4]   = {32*3*9, 64*32*9, 128*64*9, 10*128};
    const int t = blockIdx.y;
    const float* s = srcs[t];
    float*       d = dsts[t];
    const int    N = ns[t];
    const float sc = fmaxf(__uint_as_float(maxb[t]), 1e-8f);  // qmax = 2^(2-1)-1 = 1
    for (int i = blockIdx.x * 256 + threadIdx.x; i < N; i += 16 * 256)
        d[i] = rintf(s[i] / sc) * sc;
}

// Exact (pad-free) entry lists per (group-of-16-co, ci).
// Stream order: row = g*CIN + ci; within a row: co_local asc, k asc.
// Entry: { co_local*9 + k , float_bits(w) }. eptr[row] prefix, eptr[rows]=end.
__global__ __launch_bounds__(1024)
void build_lists(const float* __restrict__ qw, int Co, int CIN,
                 int* __restrict__ eptr, int2* __restrict__ E) {
    const int ngrp = Co / 16;
    const int rows = ngrp * CIN;      // max 512 (conv3)
    __shared__ int cnt[512];
    const int t = threadIdx.x;
    for (int r = t; r < rows; r += 1024) {
        const int g = r / CIN, ci = r - g * CIN;
        int n = 0;
        for (int cl = 0; cl < 16; ++cl)
            for (int k = 0; k < 9; ++k)
                if (qw[((g * 16 + cl) * CIN + ci) * 9 + k] != 0.f) ++n;
        cnt[r] = n;
    }
    __syncthreads();
    if (t == 0) {
        int s = 0;
        for (int r = 0; r < rows; ++r) {
            const int c = cnt[r];
            cnt[r] = s; eptr[r] = s; s += c;
        }
        eptr[rows] = s;
    }
    __syncthreads();
    for (int r = t; r < rows; r += 1024) {
        const int g = r / CIN, ci = r - g * CIN;
        int pos = cnt[r];
        for (int cl = 0; cl < 16; ++cl)
            for (int k = 0; k < 9; ++k) {
                const float w = qw[((g * 16 + cl) * CIN + ci) * 9 + k];
                if (w != 0.f)
                    E[pos++] = make_int2(cl * 9 + k, __float_as_int(w));
            }
    }
}

#define CASE1(CO,K)                                                      \
    case (CO)*9+(K):                                                     \
        acc[CO][0] = fmaf(coef, p[(K)/3+0][(K)%3+0], acc[CO][0]);        \
        acc[CO][1] = fmaf(coef, p[(K)/3+0][(K)%3+1], acc[CO][1]);        \
        acc[CO][2] = fmaf(coef, p[(K)/3+1][(K)%3+0], acc[CO][2]);        \
        acc[CO][3] = fmaf(coef, p[(K)/3+1][(K)%3+1], acc[CO][3]);        \
        break;
#define CASE9(CO) CASE1(CO,0) CASE1(CO,1) CASE1(CO,2) CASE1(CO,3) \
                  CASE1(CO,4) CASE1(CO,5) CASE1(CO,6) CASE1(CO,7) CASE1(CO,8)

// Sparse fused conv3x3(pad=1) + maxpool2 + quant_act.
// 16x16 threads over a 16x16 pooled tile (32x32 conv px, 34x34 input tile).
// ci staged in chunks of 8 (flat slots tid+256*s, conflict-free ds_writes).
// Per ci: dense 4x4 register patch (8 aligned b64), then exact entry list
// dispatched through a wave-uniform 144-case switch (4 FMAs per entry).
template<int CIN, int Co>
__global__ __launch_bounds__(256, 4)
void conv_sparse(const float* __restrict__ in, const int* __restrict__ eptr,
                 const int2* __restrict__ E,
                 const float* __restrict__ alpha_p, float* __restrict__ out,
                 int H, int W) {
    constexpr int NCHUNK = (CIN + 7) / 8;
    constexpr int CCH    = (CIN < 8) ? CIN : 8;
    constexpr int NGRP   = Co / 16;
    const int PH = H >> 1, PW = W >> 1;
    const int tx = threadIdx.x, ty = threadIdx.y;
    const int tid = ty * 16 + tx;
    const int b   = blockIdx.z / NGRP;
    const int grp = blockIdx.z % NGRP;
    const int px  = blockIdx.x * 16 + tx;
    const int py  = blockIdx.y * 16 + ty;
    const int ix0 = blockIdx.x * 32 - 1;
    const int iy0 = blockIdx.y * 32 - 1;

    __shared__ float tile[CCH * 1156];           // chunk-local [ci][34*34] flat
    const size_t HW = (size_t)H * W;
    const float* inB = in + (size_t)b * CIN * HW;

    // Flat staging slots hoisted once; -1 = zero-fill (pad / out of image).
    int sidx[5];
    #pragma unroll
    for (int s = 0; s < 5; ++s) {
        const int idx = tid + 256 * s;
        const int r = idx / 34, c = idx - r * 34;
        const int gy = iy0 + r, gx = ix0 + c;
        sidx[s] = (idx < 1156 && gy >= 0 && gy < H && gx >= 0 && gx < W)
                  ? (gy * W + gx) : -1;
    }

    float acc[16][4];
    #pragma unroll
    for (int c = 0; c < 16; ++c)
        #pragma unroll
        for (int q = 0; q < 4; ++q) acc[c][q] = 0.f;

    const int base = (2 * ty) * 34 + 2 * tx;     // even -> b64-aligned rows

    #pragma unroll 1
    for (int chunk = 0; chunk < NCHUNK; ++chunk) {
        if (chunk) __syncthreads();               // protect previous compute
        const int ch0 = chunk * 8;
        #pragma unroll
        for (int ch = 0; ch < CCH; ++ch) {
            const float* inC = inB + (size_t)(ch0 + ch) * HW;
            #pragma unroll
            for (int s = 0; s < 5; ++s) {
                const int idx = tid + 256 * s;    // imm-offset ds_write
                if (s < 4 || idx < 1156) {
                    const int g = sidx[s];
                    float v = 0.f;
                    if (g >= 0) v = inC[g];
                    tile[ch * 1156 + idx] = v;
                }
            }
        }
        __syncthreads();

        #pragma unroll 1
        for (int cl = 0; cl < CCH; ++cl) {
            const int row = grp * CIN + (ch0 + cl);
            const int e0 = eptr[row], e1 = eptr[row + 1];   // uniform
            if (e0 == e1) continue;

            // 4x4 patch: all nine k-stencils for this thread's 2x2 outputs.
            float p[4][4];
            const float* tb = tile + cl * 1156 + base;
            #pragma unroll
            for (int r = 0; r < 4; ++r) {
                const float2 a = *(const float2*)&tb[r * 34];
                const float2 c2 = *(const float2*)&tb[r * 34 + 2];
                p[r][0] = a.x; p[r][1] = a.y; p[r][2] = c2.x; p[r][3] = c2.y;
            }

            #pragma unroll 1
            for (int e = e0; e < e1; ++e) {
                const int2 ent = E[e];
                const int sel  = __builtin_amdgcn_readfirstlane(ent.x);
                const float coef =
                    __int_as_float(__builtin_amdgcn_readfirstlane(ent.y));
                switch (sel) {
                    CASE9(0)  CASE9(1)  CASE9(2)  CASE9(3)
                    CASE9(4)  CASE9(5)  CASE9(6)  CASE9(7)
                    CASE9(8)  CASE9(9)  CASE9(10) CASE9(11)
                    CASE9(12) CASE9(13) CASE9(14) CASE9(15)
                }
            }
        }
    }

    if (py < PH && px < PW) {
        const float alpha = *alpha_p;
        const float scale = alpha / 3.0f;         // 2^ABITS - 1 = 3
        #pragma unroll
        for (int c = 0; c < 16; ++c) {
            const float m = fmaxf(fmaxf(acc[c][0], acc[c][1]),
                                  fmaxf(acc[c][2], acc[c][3]));
            const float y = fminf(fmaxf(m, 0.f), alpha);
            out[(((size_t)b * Co + grp * 16 + c) * PH + py) * PW + px] =
                rintf(y / scale) * scale;
        }
    }
}

// One wave per (channel, batch): global max over 28x28.
__global__ __launch_bounds__(64)
void gmax_kernel(const float* __restrict__ h3, float* __restrict__ g) {
    const int c = blockIdx.x, b = blockIdx.y;
    const float* p = h3 + ((size_t)b * 128 + c) * 784;
    float m = -INFINITY;
    for (int i = threadIdx.x; i < 784; i += 64) m = fmaxf(m, p[i]);
    #pragma unroll
    for (int o = 32; o > 0; o >>= 1) m = fmaxf(m, __shfl_down(m, o));
    if (threadIdx.x == 0) g[b * 128 + c] = m;
}

// 1x1 conv 128->10 per batch (same k-ascending FMA order as round 1).
__global__ __launch_bounds__(128)
void classify_kernel(const float* __restrict__ g, const float* __restrict__ qwc,
                     float* __restrict__ out) {
    const int b = blockIdx.x;
    __shared__ float gg[128];
    gg[threadIdx.x] = g[b * 128 + threadIdx.x];
    __syncthreads();
    if (threadIdx.x < 10) {
        float s = 0.f;
        for (int k = 0; k < 128; ++k) s += qwc[threadIdx.x * 128 + k] * gg[k];
        out[b * 10 + threadIdx.x] = s;
    }
}

extern "C" void kernel_launch(void* const* d_in, const int* in_sizes, int n_in,
                              void* d_out, int out_size, void* d_ws, size_t ws_size,
                              hipStream_t stream) {
    const float* x  = (const float*)d_in[0];
    const float* w1 = (const float*)d_in[1];
    const float* w2 = (const float*)d_in[2];
    const float* w3 = (const float*)d_in[3];
    const float* wc = (const float*)d_in[4];
    const float* a1 = (const float*)d_in[5];
    const float* a2 = (const float*)d_in[6];
    const float* a3 = (const float*)d_in[7];

    float* ws = (float*)d_ws;
    size_t o = 0;
    float* qw1 = ws + o; o += 32 * 3 * 9;           // 864
    float* qw2 = ws + o; o += 64 * 32 * 9;          // 18432
    float* qw3 = ws + o; o += 128 * 64 * 9;         // 73728
    float* qwc = ws + o; o += 10 * 128;
    unsigned* maxb = (unsigned*)(ws + o); o += 4;
    float* g   = ws + o; o += 32 * 128;
    int*   ep1 = (int*)(ws + o); o += 8;            // 2*3+1 = 7
    int*   ep2 = (int*)(ws + o); o += 132;          // 4*32+1 = 129
    int*   ep3 = (int*)(ws + o); o += 516;          // 8*64+1 = 513  (o even)
    int2*  E1  = (int2*)(ws + o); o += 2UL * 864;   // dense upper bound
    int2*  E2  = (int2*)(ws + o); o += 2UL * 18432;
    int2*  E3  = (int2*)(ws + o); o += 2UL * 73728;
    float* h1p = ws + o; o += 32UL * 32 * 112 * 112;
    float* h2p = ws + o; o += 32UL * 64 * 56 * 56;
    float* h3p = ws + o; o += 32UL * 128 * 28 * 28;

    prep_zero<<<1, 64, 0, stream>>>(maxb);
    prep_absmax<<<dim3(16, 4), 256, 0, stream>>>(w1, w2, w3, wc, maxb);
    prep_quant<<<dim3(16, 4), 256, 0, stream>>>(w1, w2, w3, wc, maxb,
                                                qw1, qw2, qw3, qwc);
    build_lists<<<1, 1024, 0, stream>>>(qw1, 32, 3,  ep1, E1);
    build_lists<<<1, 1024, 0, stream>>>(qw2, 64, 32, ep2, E2);
    build_lists<<<1, 1024, 0, stream>>>(qw3, 128, 64, ep3, E3);

    // conv1: 3->32, 224x224 -> pooled 112x112. tiles 7x7, z = 32b * 2 grp
    conv_sparse<3, 32><<<dim3(7, 7, 32 * 2), dim3(16, 16), 0, stream>>>(
        x, ep1, E1, a1, h1p, 224, 224);
    // conv2: 32->64, pooled 56x56. tiles 4x4, z = 32b * 4 grp
    conv_sparse<32, 64><<<dim3(4, 4, 32 * 4), dim3(16, 16), 0, stream>>>(
        h1p, ep2, E2, a2, h2p, 112, 112);
    // conv3: 64->128, pooled 28x28. tiles 2x2, z = 32b * 8 grp
    conv_sparse<64, 128><<<dim3(2, 2, 32 * 8), dim3(16, 16), 0, stream>>>(
        h2p, ep3, E3, a3, h3p, 56, 56);

    gmax_kernel<<<dim3(128, 32), 64, 0, stream>>>(h3p, g);
    classify_kernel<<<32, 128, 0, stream>>>(g, qwc, (float*)d_out);
}

// Round 11
// 630.690 us; speedup vs baseline: 1.1418x; 1.1418x over previous
//
#include <hip/hip_runtime.h>
#include <hip/hip_bf16.h>
#include <math.h>

// ---------------------------------------------------------------------------
// Quantized CNN forward (bitwise-exact vs fp32 reference):
//   block_k: maxpool2( quant_act( conv3x3(x, quant_weight(wk)), ak ) )
//   then global max over HxW, then 1x1 conv (10x128).
// Sparse formulation (R7+, absmax 0.0): ternary weights ~96% zero; zero-weight
// FMAs are skippable bitwise-safely; nonzeros applied (ci asc, k asc) per co.
//
// R11: R8/R9 slot-major padding inflated LDS work 2.5x; R10's per-entry jump
// table serialized + AGPR-churned. This round: EXACT per-(co,chunk) lists +
// GUARDED ROUND-ROBIN interleave of NCO=8 lists (uniform s_cbranch skips,
// ~6cyc vs a pad entry's 4 LDS reads) + direct ds_read2_b32 patch reads
// (2 LDS instr/entry). acc[8][4]=32 regs -> no AGPR pressure. No sort/perm.
// ---------------------------------------------------------------------------

__global__ __launch_bounds__(64)
void prep_zero(unsigned* __restrict__ maxb) {
    if (threadIdx.x < 4) maxb[threadIdx.x] = 0u;
}

__global__ __launch_bounds__(256)
void prep_absmax(const float* __restrict__ w1, const float* __restrict__ w2,
                 const float* __restrict__ w3, const float* __restrict__ wc,
                 unsigned* __restrict__ maxb) {
    const float* srcs[4] = {w1, w2, w3, wc};
    const int    ns[4]   = {32*3*9, 64*32*9, 128*64*9, 10*128};
    const int t = blockIdx.y;
    const float* s = srcs[t];
    const int    N = ns[t];
    float m = 0.f;
    for (int i = blockIdx.x * 256 + threadIdx.x; i < N; i += 16 * 256)
        m = fmaxf(m, fabsf(s[i]));
    #pragma unroll
    for (int o = 32; o > 0; o >>= 1) m = fmaxf(m, __shfl_down(m, o));
    __shared__ float red[4];
    const int lane = threadIdx.x & 63, wid = threadIdx.x >> 6;
    if (lane == 0) red[wid] = m;
    __syncthreads();
    if (threadIdx.x == 0) {
        float mm = fmaxf(fmaxf(red[0], red[1]), fmaxf(red[2], red[3]));
        atomicMax(maxb + t, __float_as_uint(mm));  // |w|>=0: uint order == float order
    }
}

__global__ __launch_bounds__(256)
void prep_quant(const float* __restrict__ w1, const float* __restrict__ w2,
                const float* __restrict__ w3, const float* __restrict__ wc,
                const unsigned* __restrict__ maxb,
                float* __restrict__ q1, float* __restrict__ q2,
                float* __restrict__ q3, float* __restrict__ qc) {
    const float* srcs[4] = {w1, w2, w3, wc};
    float*       dsts[4] = {q1, q2, q3, qc};
    const int    ns[4]   = {32*3*9, 64*32*9, 128*64*9, 10*128};
    const int t = blockIdx.y;
    const float* s = srcs[t];
    float*       d = dsts[t];
    const int    N = ns[t];
    const float sc = fmaxf(__uint_as_float(maxb[t]), 1e-8f);  // qmax = 2^(2-1)-1 = 1
    for (int i = blockIdx.x * 256 + threadIdx.x; i < N; i += 16 * 256)
        d[i] = rintf(s[i] / sc) * sc;
}

// Exact per-row entry lists. Row order: (group-of-8-co, ci-chunk, co_local);
// within a row: (ci asc within chunk, k asc) — the reference accumulation
// order per co. Entry { (ci_local*1156 + ky*34 + kx), float_bits(w) }.
// rowptr has ngrp*nchunk*8 + 1 entries (global prefix; rows contiguous).
__global__ __launch_bounds__(1024)
void build_rows(const float* __restrict__ qw, int Co, int CIN,
                int* __restrict__ rowptr, int2* __restrict__ E) {
    const int ngrp = Co / 8;
    const int nchunk = (CIN + 7) / 8;
    const int rows = ngrp * nchunk * 8;     // max 1024 (conv3)
    __shared__ int cnt[1024];
    const int t = threadIdx.x;
    for (int r = t; r < rows; r += 1024) {
        const int c = r & 7, gc = r >> 3;
        const int g = gc / nchunk, ch = gc - g * nchunk;
        const int co = g * 8 + c;
        const int c0 = ch * 8, c1 = min(CIN, c0 + 8);
        int n = 0;
        for (int ci = c0; ci < c1; ++ci)
            for (int k = 0; k < 9; ++k)
                if (qw[(co * CIN + ci) * 9 + k] != 0.f) ++n;
        cnt[r] = n;
    }
    __syncthreads();
    if (t == 0) {
        int s = 0;
        for (int r = 0; r < rows; ++r) {
            const int c = cnt[r];
            cnt[r] = s; rowptr[r] = s; s += c;
        }
        rowptr[rows] = s;
    }
    __syncthreads();
    for (int r = t; r < rows; r += 1024) {
        const int c = r & 7, gc = r >> 3;
        const int g = gc / nchunk, ch = gc - g * nchunk;
        const int co = g * 8 + c;
        const int c0 = ch * 8, c1 = min(CIN, c0 + 8);
        int pos = cnt[r];
        for (int ci = c0; ci < c1; ++ci)
            for (int k = 0; k < 9; ++k) {
                const float w = qw[(co * CIN + ci) * 9 + k];
                if (w != 0.f)
                    E[pos++] = make_int2((ci - c0) * 1156 + (k / 3) * 34 + (k % 3),
                                         __float_as_int(w));
            }
    }
}

// Sparse fused conv3x3(pad=1) + maxpool2 + quant_act.
// 16x16 threads over a 16x16 pooled tile (32x32 conv px, 34x34 input tile).
// ci staged in chunks of 8 (flat slots tid+256*s, conflict-free ds_writes).
// Compute: guarded round-robin over the group's 8 exact lists — round r
// applies entry r of every co with len>r (uniform skip otherwise). Patch
// words read directly: tp[0],tp[1],tp[34],tp[35] -> 2x ds_read2_b32.
template<int CIN, int Co>
__global__ __launch_bounds__(256, 4)
void conv_sparse(const float* __restrict__ in, const int* __restrict__ rowptr,
                 const int2* __restrict__ E,
                 const float* __restrict__ alpha_p, float* __restrict__ out,
                 int H, int W) {
    constexpr int NCHUNK = (CIN + 7) / 8;
    constexpr int CCH    = (CIN < 8) ? CIN : 8;
    constexpr int NGRP   = Co / 8;
    const int PH = H >> 1, PW = W >> 1;
    const int tx = threadIdx.x, ty = threadIdx.y;
    const int tid = ty * 16 + tx;
    const int b   = blockIdx.z / NGRP;
    const int grp = blockIdx.z % NGRP;
    const int px  = blockIdx.x * 16 + tx;
    const int py  = blockIdx.y * 16 + ty;
    const int ix0 = blockIdx.x * 32 - 1;
    const int iy0 = blockIdx.y * 32 - 1;

    __shared__ float tile[CCH * 1156];           // chunk-local [ci][34*34] flat
    const size_t HW = (size_t)H * W;
    const float* inB = in + (size_t)b * CIN * HW;

    // Flat staging slots hoisted once; -1 = zero-fill (pad / out of image).
    int sidx[5];
    #pragma unroll
    for (int s = 0; s < 5; ++s) {
        const int idx = tid + 256 * s;
        const int r = idx / 34, c = idx - r * 34;
        const int gy = iy0 + r, gx = ix0 + c;
        sidx[s] = (idx < 1156 && gy >= 0 && gy < H && gx >= 0 && gx < W)
                  ? (gy * W + gx) : -1;
    }

    float acc[8][4];
    #pragma unroll
    for (int c = 0; c < 8; ++c)
        #pragma unroll
        for (int q = 0; q < 4; ++q) acc[c][q] = 0.f;

    const int base = (2 * ty) * 34 + 2 * tx;     // word offset of thread's patch

    #pragma unroll 1
    for (int chunk = 0; chunk < NCHUNK; ++chunk) {
        if (chunk) __syncthreads();               // protect previous compute
        const int ch0 = chunk * 8;
        #pragma unroll
        for (int ch = 0; ch < CCH; ++ch) {
            const float* inC = inB + (size_t)(ch0 + ch) * HW;
            #pragma unroll
            for (int s = 0; s < 5; ++s) {
                const int idx = tid + 256 * s;    // imm-offset ds_write
                if (s < 4 || idx < 1156) {
                    const int g = sidx[s];
                    float v = 0.f;
                    if (g >= 0) v = inC[g];
                    tile[ch * 1156 + idx] = v;
                }
            }
        }
        __syncthreads();

        // 9 uniform row pointers for this (group, chunk) -> scalar regs.
        const int rowbase = (grp * NCHUNK + chunk) * 8;
        int rp[9];
        #pragma unroll
        for (int j = 0; j < 9; ++j) rp[j] = rowptr[rowbase + j];
        int mx = 0;
        #pragma unroll
        for (int c = 0; c < 8; ++c) mx = max(mx, rp[c + 1] - rp[c]);

        #pragma unroll 1
        for (int r = 0; r < mx; ++r) {
            #pragma unroll
            for (int c = 0; c < 8; ++c) {
                if (r < rp[c + 1] - rp[c]) {      // uniform guard (s_cbranch)
                    const int2 ent = E[rp[c] + r];
                    const int off =
                        __builtin_amdgcn_readfirstlane(ent.x);
                    const float coef =
                        __int_as_float(__builtin_amdgcn_readfirstlane(ent.y));
                    const float* tp = tile + off + base;
                    acc[c][0] = fmaf(coef, tp[0],  acc[c][0]);
                    acc[c][1] = fmaf(coef, tp[1],  acc[c][1]);
                    acc[c][2] = fmaf(coef, tp[34], acc[c][2]);
                    acc[c][3] = fmaf(coef, tp[35], acc[c][3]);
                }
            }
        }
    }

    if (py < PH && px < PW) {
        const float alpha = *alpha_p;
        const float scale = alpha / 3.0f;         // 2^ABITS - 1 = 3
        #pragma unroll
        for (int c = 0; c < 8; ++c) {
            const float m = fmaxf(fmaxf(acc[c][0], acc[c][1]),
                                  fmaxf(acc[c][2], acc[c][3]));
            const float y = fminf(fmaxf(m, 0.f), alpha);
            out[(((size_t)b * Co + grp * 8 + c) * PH + py) * PW + px] =
                rintf(y / scale) * scale;
        }
    }
}

// One wave per (channel, batch): global max over 28x28.
__global__ __launch_bounds__(64)
void gmax_kernel(const float* __restrict__ h3, float* __restrict__ g) {
    const int c = blockIdx.x, b = blockIdx.y;
    const float* p = h3 + ((size_t)b * 128 + c) * 784;
    float m = -INFINITY;
    for (int i = threadIdx.x; i < 784; i += 64) m = fmaxf(m, p[i]);
    #pragma unroll
    for (int o = 32; o > 0; o >>= 1) m = fmaxf(m, __shfl_down(m, o));
    if (threadIdx.x == 0) g[b * 128 + c] = m;
}

// 1x1 conv 128->10 per batch (same k-ascending FMA order as round 1).
__global__ __launch_bounds__(128)
void classify_kernel(const float* __restrict__ g, const float* __restrict__ qwc,
                     float* __restrict__ out) {
    const int b = blockIdx.x;
    __shared__ float gg[128];
    gg[threadIdx.x] = g[b * 128 + threadIdx.x];
    __syncthreads();
    if (threadIdx.x < 10) {
        float s = 0.f;
        for (int k = 0; k < 128; ++k) s += qwc[threadIdx.x * 128 + k] * gg[k];
        out[b * 10 + threadIdx.x] = s;
    }
}

extern "C" void kernel_launch(void* const* d_in, const int* in_sizes, int n_in,
                              void* d_out, int out_size, void* d_ws, size_t ws_size,
                              hipStream_t stream) {
    const float* x  = (const float*)d_in[0];
    const float* w1 = (const float*)d_in[1];
    const float* w2 = (const float*)d_in[2];
    const float* w3 = (const float*)d_in[3];
    const float* wc = (const float*)d_in[4];
    const float* a1 = (const float*)d_in[5];
    const float* a2 = (const float*)d_in[6];
    const float* a3 = (const float*)d_in[7];

    float* ws = (float*)d_ws;
    size_t o = 0;
    float* qw1 = ws + o; o += 32 * 3 * 9;           // 864
    float* qw2 = ws + o; o += 64 * 32 * 9;          // 18432
    float* qw3 = ws + o; o += 128 * 64 * 9;         // 73728
    float* qwc = ws + o; o += 10 * 128;
    unsigned* maxb = (unsigned*)(ws + o); o += 4;
    float* g   = ws + o; o += 32 * 128;
    int*   rp1 = (int*)(ws + o); o += 36;           // 4*1*8+1 = 33
    int*   rp2 = (int*)(ws + o); o += 260;          // 8*4*8+1 = 257
    int*   rp3 = (int*)(ws + o); o += 1028;         // 16*8*8+1 = 1025 (o even)
    int2*  E1  = (int2*)(ws + o); o += 2UL * 864;   // dense upper bound
    int2*  E2  = (int2*)(ws + o); o += 2UL * 18432;
    int2*  E3  = (int2*)(ws + o); o += 2UL * 73728;
    float* h1p = ws + o; o += 32UL * 32 * 112 * 112;
    float* h2p = ws + o; o += 32UL * 64 * 56 * 56;
    float* h3p = ws + o; o += 32UL * 128 * 28 * 28;

    prep_zero<<<1, 64, 0, stream>>>(maxb);
    prep_absmax<<<dim3(16, 4), 256, 0, stream>>>(w1, w2, w3, wc, maxb);
    prep_quant<<<dim3(16, 4), 256, 0, stream>>>(w1, w2, w3, wc, maxb,
                                                qw1, qw2, qw3, qwc);
    build_rows<<<1, 1024, 0, stream>>>(qw1, 32, 3,  rp1, E1);
    build_rows<<<1, 1024, 0, stream>>>(qw2, 64, 32, rp2, E2);
    build_rows<<<1, 1024, 0, stream>>>(qw3, 128, 64, rp3, E3);

    // conv1: 3->32, 224x224 -> pooled 112x112. tiles 7x7, z = 32b * 4 grp
    conv_sparse<3, 32><<<dim3(7, 7, 32 * 4), dim3(16, 16), 0, stream>>>(
        x, rp1, E1, a1, h1p, 224, 224);
    // conv2: 32->64, pooled 56x56. tiles 4x4, z = 32b * 8 grp
    conv_sparse<32, 64><<<dim3(4, 4, 32 * 8), dim3(16, 16), 0, stream>>>(
        h1p, rp2, E2, a2, h2p, 112, 112);
    // conv3: 64->128, pooled 28x28. tiles 2x2, z = 32b * 16 grp
    conv_sparse<64, 128><<<dim3(2, 2, 32 * 16), dim3(16, 16), 0, stream>>>(
        h2p, rp3, E3, a3, h3p, 56, 56);

    gmax_kernel<<<dim3(128, 32), 64, 0, stream>>>(h3p, g);
    classify_kernel<<<32, 128, 0, stream>>>(g, qwc, (float*)d_out);
}

// Round 12
// 576.438 us; speedup vs baseline: 1.2493x; 1.0941x over previous
//
#include <hip/hip_runtime.h>
#include <hip/hip_bf16.h>
#include <math.h>

// ---------------------------------------------------------------------------
// Quantized CNN forward (bitwise-exact vs fp32 reference):
//   block_k: maxpool2( quant_act( conv3x3(x, quant_weight(wk)), ak ) )
//   then global max over HxW, then 1x1 conv (10x128).
// Sparse formulation (R7+, absmax 0.0): ternary weights ~96% zero; skipping
// all-zero work is bitwise-safe; per-co accumulation stays (ci asc, k asc).
//
// R12: per-ENTRY granularity (R8-R11) always lost: padded variants are
// LDS-instr-bound, exact variants latency-bound (4-FMA bodies behind branches
// can't amortize fetch latency; R11 VALUBusy 11.5%). This round coarsens the
// quantum: only ~27% of (co,ci) PAIRS are nonzero (1-0.965^9). Per ci: dense
// 4x4 register patch (8 ds_read_b64, all nine k-stencils); per co: one uniform
// bit-test (128-bit pair mask) guarding a straight-line 36-FMA body; 9 coefs
// via 16B-aligned padded table -> s_load_dwordx4 (SGPR operands, no VGPR w[]).
// Included pairs compute the reference's full dense k-sum (zero coefs incl.)
// in reference order; skipped pairs are 9 zero-FMAs (bitwise-safe).
// acc[16][4]+patch+staging ~100 VGPR -> fits (256,4), no AGPRs. NCO=16 also
// halves z-groups vs R11 (staging/FETCH ~2x down).
// ---------------------------------------------------------------------------

__global__ __launch_bounds__(64)
void prep_zero(unsigned* __restrict__ maxb) {
    if (threadIdx.x < 4) maxb[threadIdx.x] = 0u;
}

__global__ __launch_bounds__(256)
void prep_absmax(const float* __restrict__ w1, const float* __restrict__ w2,
                 const float* __restrict__ w3, const float* __restrict__ wc,
                 unsigned* __restrict__ maxb) {
    const float* srcs[4] = {w1, w2, w3, wc};
    const int    ns[4]   = {32*3*9, 64*32*9, 128*64*9, 10*128};
    const int t = blockIdx.y;
    const float* s = srcs[t];
    const int    N = ns[t];
    float m = 0.f;
    for (int i = blockIdx.x * 256 + threadIdx.x; i < N; i += 16 * 256)
        m = fmaxf(m, fabsf(s[i]));
    #pragma unroll
    for (int o = 32; o > 0; o >>= 1) m = fmaxf(m, __shfl_down(m, o));
    __shared__ float red[4];
    const int lane = threadIdx.x & 63, wid = threadIdx.x >> 6;
    if (lane == 0) red[wid] = m;
    __syncthreads();
    if (threadIdx.x == 0) {
        float mm = fmaxf(fmaxf(red[0], red[1]), fmaxf(red[2], red[3]));
        atomicMax(maxb + t, __float_as_uint(mm));  // |w|>=0: uint order == float order
    }
}

__global__ __launch_bounds__(256)
void prep_quant(const float* __restrict__ w1, const float* __restrict__ w2,
                const float* __restrict__ w3, const float* __restrict__ wc,
                const unsigned* __restrict__ maxb,
                float* __restrict__ q1, float* __restrict__ q2,
                float* __restrict__ q3, float* __restrict__ qc) {
    const float* srcs[4] = {w1, w2, w3, wc};
    float*       dsts[4] = {q1, q2, q3, qc};
    const int    ns[4]   = {32*3*9, 64*32*9, 128*64*9, 10*128};
    const int t = blockIdx.y;
    const float* s = srcs[t];
    float*       d = dsts[t];
    const int    N = ns[t];
    const float sc = fmaxf(__uint_as_float(maxb[t]), 1e-8f);  // qmax = 2^(2-1)-1 = 1
    for (int i = blockIdx.x * 256 + threadIdx.x; i < N; i += 16 * 256)
        d[i] = rintf(s[i] / sc) * sc;
}

// Build (a) 128-bit pair masks per (grp-of-16-co, ci-chunk-of-8): bit
// (ci_local*16 + c) set iff pair (co=grp*16+c, ci=chunk*8+ci_local) has any
// nonzero weight; (b) padded coef table cw: 12-float (16B-aligned) rows,
// row = ((grp*nchunk+chunk)*8 + ci_local)*16 + c, coefs k=0..8 then 3 zeros.
__global__ __launch_bounds__(256)
void build_masks(const float* __restrict__ qw, int Co, int CIN,
                 unsigned* __restrict__ masks, float* __restrict__ cw) {
    const int nchunk = (CIN + 7) / 8;
    const int ngrp = Co / 16;
    const int ndw = ngrp * nchunk * 4;
    const int t = threadIdx.x;
    for (int i = t; i < ndw; i += 256) {
        const int row = i >> 2, d = i & 3;
        const int grp = row / nchunk, ch = row - grp * nchunk;
        unsigned m = 0;
        for (int bit = 0; bit < 32; ++bit) {
            const int lin = d * 32 + bit;          // ci_local*16 + c
            const int cil = lin >> 4, c = lin & 15;
            const int ci = ch * 8 + cil, co = grp * 16 + c;
            if (ci < CIN) {
                bool nz = false;
                for (int k = 0; k < 9; ++k)
                    nz |= (qw[(co * CIN + ci) * 9 + k] != 0.f);
                if (nz) m |= (1u << bit);
            }
        }
        masks[i] = m;
    }
    const int npair = ngrp * nchunk * 8 * 16;
    for (int pidx = t; pidx < npair; pidx += 256) {
        const int c = pidx & 15, rest = pidx >> 4;
        const int cil = rest & 7, row2 = rest >> 3;
        const int grp = row2 / nchunk, ch = row2 - grp * nchunk;
        const int ci = ch * 8 + cil, co = grp * 16 + c;
        float* dst = cw + (size_t)pidx * 12;
        #pragma unroll
        for (int k = 0; k < 9; ++k)
            dst[k] = (ci < CIN) ? qw[(co * CIN + ci) * 9 + k] : 0.f;
        dst[9] = dst[10] = dst[11] = 0.f;
    }
}

// Sparse fused conv3x3(pad=1) + maxpool2 + quant_act.
// 16x16 threads over a 16x16 pooled tile (32x32 conv px, 34x34 input tile).
// ci staged in chunks of 8 (flat slots tid+256*s, conflict-free ds_writes).
// Per ci: dense 4x4 patch (8 ds_read_b64); per co: uniform bit-test guarding
// a straight-line 36-FMA body with scalar-loaded coefs.
template<int CIN, int Co>
__global__ __launch_bounds__(256, 4)
void conv_sparse(const float* __restrict__ in, const unsigned* __restrict__ masks,
                 const float* __restrict__ cw,
                 const float* __restrict__ alpha_p, float* __restrict__ out,
                 int H, int W) {
    constexpr int NCHUNK = (CIN + 7) / 8;
    constexpr int CCH    = (CIN < 8) ? CIN : 8;
    constexpr int NGRP   = Co / 16;
    const int PH = H >> 1, PW = W >> 1;
    const int tx = threadIdx.x, ty = threadIdx.y;
    const int tid = ty * 16 + tx;
    const int b   = blockIdx.z / NGRP;
    const int grp = blockIdx.z % NGRP;
    const int px  = blockIdx.x * 16 + tx;
    const int py  = blockIdx.y * 16 + ty;
    const int ix0 = blockIdx.x * 32 - 1;
    const int iy0 = blockIdx.y * 32 - 1;

    __shared__ float tile[CCH * 1156];           // chunk-local [ci][34*34] flat
    const size_t HW = (size_t)H * W;
    const float* inB = in + (size_t)b * CIN * HW;

    // Flat staging slots hoisted once; -1 = zero-fill (pad / out of image).
    int sidx[5];
    #pragma unroll
    for (int s = 0; s < 5; ++s) {
        const int idx = tid + 256 * s;
        const int r = idx / 34, c = idx - r * 34;
        const int gy = iy0 + r, gx = ix0 + c;
        sidx[s] = (idx < 1156 && gy >= 0 && gy < H && gx >= 0 && gx < W)
                  ? (gy * W + gx) : -1;
    }

    float acc[16][4];
    #pragma unroll
    for (int c = 0; c < 16; ++c)
        #pragma unroll
        for (int q = 0; q < 4; ++q) acc[c][q] = 0.f;

    const int base = (2 * ty) * 34 + 2 * tx;     // even -> b64-aligned reads

    #pragma unroll 1
    for (int chunk = 0; chunk < NCHUNK; ++chunk) {
        if (chunk) __syncthreads();               // protect previous compute
        const int ch0 = chunk * 8;
        #pragma unroll
        for (int ch = 0; ch < CCH; ++ch) {
            const float* inC = inB + (size_t)(ch0 + ch) * HW;
            #pragma unroll
            for (int s = 0; s < 5; ++s) {
                const int idx = tid + 256 * s;    // imm-offset ds_write
                if (s < 4 || idx < 1156) {
                    const int g = sidx[s];
                    float v = 0.f;
                    if (g >= 0) v = inC[g];
                    tile[ch * 1156 + idx] = v;
                }
            }
        }
        __syncthreads();

        // 128-bit pair mask for (grp, chunk) -> scalar regs.
        const unsigned* mp = masks + (size_t)(grp * NCHUNK + chunk) * 4;
        unsigned mvec[4];
        #pragma unroll
        for (int d = 0; d < 4; ++d)
            mvec[d] = __builtin_amdgcn_readfirstlane(mp[d]);

        const float* cwc = cw + (size_t)((grp * NCHUNK + chunk) * 8) * 16 * 12;

        #pragma unroll 1
        for (int cil = 0; cil < CCH; ++cil) {
            const unsigned m16 = (mvec[cil >> 1] >> ((cil & 1) * 16)) & 0xffffu;
            if (!m16) continue;

            // Dense 4x4 patch: all nine k-stencils for the 2x2 outputs.
            float p[4][4];
            const float* tb = tile + cil * 1156 + base;
            #pragma unroll
            for (int r = 0; r < 4; ++r) {
                const float2 a  = *(const float2*)&tb[r * 34];
                const float2 c2 = *(const float2*)&tb[r * 34 + 2];
                p[r][0] = a.x; p[r][1] = a.y; p[r][2] = c2.x; p[r][3] = c2.y;
            }

            const float* cwr = cwc + (size_t)cil * 16 * 12;
            #pragma unroll
            for (int c = 0; c < 16; ++c) {
                if (m16 & (1u << c)) {            // uniform s_bitcmp+s_cbranch
                    const float* wp = cwr + c * 12;   // 16B-aligned row
                    #pragma unroll
                    for (int k = 0; k < 9; ++k) {
                        const float w = wp[k];        // uniform -> s_load
                        acc[c][0] = fmaf(w, p[k/3    ][k%3    ], acc[c][0]);
                        acc[c][1] = fmaf(w, p[k/3    ][k%3 + 1], acc[c][1]);
                        acc[c][2] = fmaf(w, p[k/3 + 1][k%3    ], acc[c][2]);
                        acc[c][3] = fmaf(w, p[k/3 + 1][k%3 + 1], acc[c][3]);
                    }
                }
            }
        }
    }

    if (py < PH && px < PW) {
        const float alpha = *alpha_p;
        const float scale = alpha / 3.0f;         // 2^ABITS - 1 = 3
        #pragma unroll
        for (int c = 0; c < 16; ++c) {
            const float m = fmaxf(fmaxf(acc[c][0], acc[c][1]),
                                  fmaxf(acc[c][2], acc[c][3]));
            const float y = fminf(fmaxf(m, 0.f), alpha);
            out[(((size_t)b * Co + grp * 16 + c) * PH + py) * PW + px] =
                rintf(y / scale) * scale;
        }
    }
}

// One wave per (channel, batch): global max over 28x28.
__global__ __launch_bounds__(64)
void gmax_kernel(const float* __restrict__ h3, float* __restrict__ g) {
    const int c = blockIdx.x, b = blockIdx.y;
    const float* p = h3 + ((size_t)b * 128 + c) * 784;
    float m = -INFINITY;
    for (int i = threadIdx.x; i < 784; i += 64) m = fmaxf(m, p[i]);
    #pragma unroll
    for (int o = 32; o > 0; o >>= 1) m = fmaxf(m, __shfl_down(m, o));
    if (threadIdx.x == 0) g[b * 128 + c] = m;
}

// 1x1 conv 128->10 per batch (same k-ascending FMA order as round 1).
__global__ __launch_bounds__(128)
void classify_kernel(const float* __restrict__ g, const float* __restrict__ qwc,
                     float* __restrict__ out) {
    const int b = blockIdx.x;
    __shared__ float gg[128];
    gg[threadIdx.x] = g[b * 128 + threadIdx.x];
    __syncthreads();
    if (threadIdx.x < 10) {
        float s = 0.f;
        for (int k = 0; k < 128; ++k) s += qwc[threadIdx.x * 128 + k] * gg[k];
        out[b * 10 + threadIdx.x] = s;
    }
}

extern "C" void kernel_launch(void* const* d_in, const int* in_sizes, int n_in,
                              void* d_out, int out_size, void* d_ws, size_t ws_size,
                              hipStream_t stream) {
    const float* x  = (const float*)d_in[0];
    const float* w1 = (const float*)d_in[1];
    const float* w2 = (const float*)d_in[2];
    const float* w3 = (const float*)d_in[3];
    const float* wc = (const float*)d_in[4];
    const float* a1 = (const float*)d_in[5];
    const float* a2 = (const float*)d_in[6];
    const float* a3 = (const float*)d_in[7];

    float* ws = (float*)d_ws;
    size_t o = 0;
    float* qw1 = ws + o; o += 32 * 3 * 9;           // 864
    float* qw2 = ws + o; o += 64 * 32 * 9;          // 18432
    float* qw3 = ws + o; o += 128 * 64 * 9;         // 73728
    float* qwc = ws + o; o += 10 * 128;             // 1280
    unsigned* maxb = (unsigned*)(ws + o); o += 4;
    float* g   = ws + o; o += 32 * 128;             // 4096
    unsigned* mk1 = (unsigned*)(ws + o); o += 8;    // 2 grp * 1 ch * 4
    unsigned* mk2 = (unsigned*)(ws + o); o += 64;   // 4 grp * 4 ch * 4
    unsigned* mk3 = (unsigned*)(ws + o); o += 256;  // 8 grp * 8 ch * 4
    float* cw1 = ws + o; o += 2UL * 1 * 8 * 16 * 12;   //  3072 (16B aligned)
    float* cw2 = ws + o; o += 4UL * 4 * 8 * 16 * 12;   // 24576
    float* cw3 = ws + o; o += 8UL * 8 * 8 * 16 * 12;   // 98304
    float* h1p = ws + o; o += 32UL * 32 * 112 * 112;
    float* h2p = ws + o; o += 32UL * 64 * 56 * 56;
    float* h3p = ws + o; o += 32UL * 128 * 28 * 28;

    prep_zero<<<1, 64, 0, stream>>>(maxb);
    prep_absmax<<<dim3(16, 4), 256, 0, stream>>>(w1, w2, w3, wc, maxb);
    prep_quant<<<dim3(16, 4), 256, 0, stream>>>(w1, w2, w3, wc, maxb,
                                                qw1, qw2, qw3, qwc);
    build_masks<<<1, 256, 0, stream>>>(qw1, 32, 3,  mk1, cw1);
    build_masks<<<1, 256, 0, stream>>>(qw2, 64, 32, mk2, cw2);
    build_masks<<<1, 256, 0, stream>>>(qw3, 128, 64, mk3, cw3);

    // conv1: 3->32, 224x224 -> pooled 112x112. tiles 7x7, z = 32b * 2 grp
    conv_sparse<3, 32><<<dim3(7, 7, 32 * 2), dim3(16, 16), 0, stream>>>(
        x, mk1, cw1, a1, h1p, 224, 224);
    // conv2: 32->64, pooled 56x56. tiles 4x4, z = 32b * 4 grp
    conv_sparse<32, 64><<<dim3(4, 4, 32 * 4), dim3(16, 16), 0, stream>>>(
        h1p, mk2, cw2, a2, h2p, 112, 112);
    // conv3: 64->128, pooled 28x28. tiles 2x2, z = 32b * 8 grp
    conv_sparse<64, 128><<<dim3(2, 2, 32 * 8), dim3(16, 16), 0, stream>>>(
        h2p, mk3, cw3, a3, h3p, 56, 56);

    gmax_kernel<<<dim3(128, 32), 64, 0, stream>>>(h3p, g);
    classify_kernel<<<32, 128, 0, stream>>>(g, qwc, (float*)d_out);
}